// Round 1
// 1989.385 us; speedup vs baseline: 1.0589x; 1.0589x over previous
//
#include <hip/hip_runtime.h>
#include <hip/hip_fp16.h>

typedef unsigned short u16;
typedef unsigned int   u32;

#define DIM    64
#define NREL   8
#define NB     4
#define NNODE  150000
#define NEDGE  1000000
#define NSEDGE 200000
#define BATCH  1024
#define SEQL   20
#define NPRED  20
#define TD     384

__device__ __forceinline__ u32 packh2(float lo, float hi) {
    __half2 h;
    h.x = __float2half_rn(lo);
    h.y = __float2half_rn(hi);
    u32 r;
    __builtin_memcpy(&r, &h, 4);
    return r;
}
__device__ __forceinline__ float2 h2pair(u32 w) {
    __half2 h;
    __builtin_memcpy(&h, &w, 4);
    return __half22float2(h);
}

// ---- W[r][d][j] = sum_b comp[r][b]*basis[b][d][j]; packed as (f16 j | f16 j+32) ----
__global__ __launch_bounds__(256) void wpack_kernel(const float* __restrict__ comp,
                                                    const float* __restrict__ basis,
                                                    u32* __restrict__ Wp) {
    int idx = blockIdx.x * 256 + threadIdx.x;     // NREL*64*32 = 16384 total
    int r = idx >> 11;
    int d = (idx >> 5) & 63;
    int jj = idx & 31;
    float c0 = comp[r * NB + 0], c1 = comp[r * NB + 1];
    float c2 = comp[r * NB + 2], c3 = comp[r * NB + 3];
    const float* b0 = basis + 0 * 4096 + d * 64 + jj;
    const float* b1 = basis + 1 * 4096 + d * 64 + jj;
    const float* b2 = basis + 2 * 4096 + d * 64 + jj;
    const float* b3 = basis + 3 * 4096 + d * 64 + jj;
    float lo = c0 * b0[0]  + c1 * b1[0]  + c2 * b2[0]  + c3 * b3[0];
    float hi = c0 * b0[32] + c1 * b1[32] + c2 * b2[32] + c3 * b3[32];
    Wp[idx] = packh2(lo, hi);
}

// ---- root packed the same way: (f16 j | f16 j+32) at [d*32+jj] ----
__global__ __launch_bounds__(256) void rpack_kernel(const float* __restrict__ root,
                                                    u32* __restrict__ Rp) {
    int idx = blockIdx.x * 256 + threadIdx.x;     // 64*32 = 2048 total
    if (idx >= 2048) return;
    int d = idx >> 5, jj = idx & 31;
    Rp[idx] = packh2(root[d * 64 + jj], root[d * 64 + jj + 32]);
}

// =================== CSR preprocessing (once per graph, reused 3 layers) ===========

// histogram of destination degrees
__global__ __launch_bounds__(256) void hist_kernel(const int* __restrict__ dst,
                                                   int* __restrict__ cnt, int E) {
    int i = blockIdx.x * 256 + threadIdx.x;
    const int stride = gridDim.x * 256;
    for (; i < E; i += stride) atomicAdd(&cnt[dst[i]], 1);
}

// allocate contiguous slot ranges per dst (order of ranges is irrelevant).
// wave-level inclusive scan of degrees, one atomicAdd on a global cursor per wave.
__global__ __launch_bounds__(256) void alloc_kernel(const int* __restrict__ cnt,
                                                    int* __restrict__ rstart,
                                                    int* __restrict__ cursor,
                                                    int* __restrict__ total, int N) {
    const int i = blockIdx.x * 256 + threadIdx.x;
    const int lane = threadIdx.x & 63;
    int deg = (i < N) ? cnt[i] : 0;
    int v = deg;
#pragma unroll
    for (int o = 1; o < 64; o <<= 1) {
        int u = __shfl_up(v, o, 64);
        if (lane >= o) v += u;
    }
    int base = 0;
    if (lane == 63) base = atomicAdd(total, v);   // v at lane63 == wave total
    base = __shfl(base, 63, 64);
    if (i < N) {
        const int st = base + v - deg;
        rstart[i] = st;
        cursor[i] = st;                            // scatter advances this to row end
    }
}

// scatter edges into their dst's slot range; pack (src | type<<18) into one u32.
// after this kernel, cursor[n] == row end offset for node n.
__global__ __launch_bounds__(256) void scatter_kernel(const int* __restrict__ src,
                                                      const int* __restrict__ dst,
                                                      const int* __restrict__ typ,
                                                      int* __restrict__ cursor,
                                                      u32* __restrict__ packed, int E) {
    int i = blockIdx.x * 256 + threadIdx.x;
    const int stride = gridDim.x * 256;
    for (; i < E; i += stride) {
        const int slot = atomicAdd(&cursor[dst[i]], 1);
        packed[slot] = (u32)src[i] | ((u32)typ[i] << 18);
    }
}

// =================== fused RGCN layer: x_out[n] = tanh( sum_{e->n} x[src]@W[et]
//                                                       + x[n]@root + bias ) ==========
// wave per dst node; lane -> (half hf, jj); per-lane partial sums over all edges,
// halves combined once at the end via shfl_xor(32). No atomics, no memset, plain store.
__global__ __launch_bounds__(512) void rgcn_fused_kernel(const float* __restrict__ x,
                                                         const u32* __restrict__ Wp,
                                                         const u32* __restrict__ Rp,
                                                         const float* __restrict__ bias,
                                                         const int* __restrict__ rstart,
                                                         const int* __restrict__ rend,
                                                         const u32* __restrict__ packed,
                                                         float* __restrict__ xout, int N) {
    __shared__ u32 Wl[NREL * 64 * 32];            // 64 KB
    __shared__ u32 Rl[64 * 32];                   // 8 KB
    __shared__ float Bl[64];
    for (int i = threadIdx.x; i < NREL * 64 * 32; i += 512) Wl[i] = Wp[i];
    for (int i = threadIdx.x; i < 2048; i += 512) Rl[i] = Rp[i];
    if (threadIdx.x < 64) Bl[threadIdx.x] = bias[threadIdx.x];
    __syncthreads();
    const int lane = threadIdx.x & 63;
    const int hf = lane >> 5;                     // which d-half this lane reduces
    const int jj = lane & 31;
    int wave = blockIdx.x * 8 + (threadIdx.x >> 6);
    const int nw = gridDim.x * 8;
    for (int n = wave; n < N; n += nw) {
        float acc0 = 0.f, acc1 = 0.f;
        int i = rstart[n];
        const int end = rend[n];
        while (i < end) {
            int m = end - i;
            if (m > 64) m = 64;
            const u32 pk = (lane < m) ? packed[i + lane] : 0u;   // coalesced 256B
            for (int t = 0; t < m; ++t) {
                const u32 p = __shfl(pk, t, 64);
                const int s = (int)(p & 0x3FFFFu);
                const int r = (int)(p >> 18);
                const float* xr = x + (size_t)s * 64 + hf * 32;
                const u32* Wr = &Wl[r * 2048 + hf * 1024 + jj];
#pragma unroll
                for (int dd = 0; dd < 32; dd += 4) {
                    const float4 xv = *(const float4*)(xr + dd);
                    float2 f;
                    f = h2pair(Wr[(dd + 0) * 32]); acc0 += xv.x * f.x; acc1 += xv.x * f.y;
                    f = h2pair(Wr[(dd + 1) * 32]); acc0 += xv.y * f.x; acc1 += xv.y * f.y;
                    f = h2pair(Wr[(dd + 2) * 32]); acc0 += xv.z * f.x; acc1 += xv.z * f.y;
                    f = h2pair(Wr[(dd + 3) * 32]); acc0 += xv.w * f.x; acc1 += xv.w * f.y;
                }
            }
            i += m;
        }
        // root term on own row
        {
            const float* xr = x + (size_t)n * 64 + hf * 32;
            const u32* Rr = &Rl[hf * 1024 + jj];
#pragma unroll
            for (int dd = 0; dd < 32; dd += 4) {
                const float4 xv = *(const float4*)(xr + dd);
                float2 f;
                f = h2pair(Rr[(dd + 0) * 32]); acc0 += xv.x * f.x; acc1 += xv.x * f.y;
                f = h2pair(Rr[(dd + 1) * 32]); acc0 += xv.y * f.x; acc1 += xv.y * f.y;
                f = h2pair(Rr[(dd + 2) * 32]); acc0 += xv.z * f.x; acc1 += xv.z * f.y;
                f = h2pair(Rr[(dd + 3) * 32]); acc0 += xv.w * f.x; acc1 += xv.w * f.y;
            }
        }
        acc0 += __shfl_xor(acc0, 32, 64);         // combine d-halves
        acc1 += __shfl_xor(acc1, 32, 64);
        const float v = hf ? acc1 : acc0;         // hf==0 -> out jj, hf==1 -> out jj+32
        xout[(size_t)n * 64 + lane] = tanhf(v + Bl[lane]);
    }
}

// ---- gather sequence rows -> f32 output column block l ----
__global__ __launch_bounds__(256) void gather_seq_kernel(const float* __restrict__ xc,
                                                         const int* __restrict__ seqs,
                                                         float* __restrict__ out_seq, int l) {
    const int lane = threadIdx.x & 63;
    int wave = blockIdx.x * 4 + (threadIdx.x >> 6);
    const int nw = gridDim.x * 4;
    for (int p = wave; p < BATCH * SEQL; p += nw) {
        const int idx = seqs[p];
        out_seq[(size_t)p * TD + l * 64 + lane] = xc[(size_t)idx * 64 + lane];
    }
}

// ---- per-batch: user row (f32 out) and msum = sum_t seq rows ----
__global__ __launch_bounds__(256) void user_msum_kernel(const float* __restrict__ xc,
                                                        const int* __restrict__ users,
                                                        const int* __restrict__ seqs,
                                                        float* __restrict__ msum,
                                                        float* __restrict__ out_user, int l) {
    const int lane = threadIdx.x & 63;
    int wave = blockIdx.x * 4 + (threadIdx.x >> 6);
    const int nw = gridDim.x * 4;
    for (int b = wave; b < BATCH; b += nw) {
        out_user[(size_t)b * TD + l * 64 + lane] = xc[(size_t)users[b] * 64 + lane];
        float m = 0.f;
        for (int t = 0; t < SEQL; ++t)
            m += xc[(size_t)seqs[b * SEQL + t] * 64 + lane];
        msum[(size_t)b * TD + l * 64 + lane] = m;
    }
}

// ---- final: s = msum @ WV (attention collapsed); res = pw.(user+s) + pb ----
__global__ __launch_bounds__(384) void final_kernel(const float* __restrict__ msum,
                                                    const float* __restrict__ user_f32,
                                                    const float* __restrict__ WV,
                                                    const float* __restrict__ pw,
                                                    const float* __restrict__ pb,
                                                    const int* __restrict__ items,
                                                    float* __restrict__ out_res) {
    __shared__ float ms[TD];
    __shared__ float uL[TD];
    const int b = blockIdx.x;
    const int o = threadIdx.x;
    ms[o] = msum[(size_t)b * TD + o];
    __syncthreads();
    float sv = 0.f;
#pragma unroll 4
    for (int d = 0; d < TD; ++d) sv += ms[d] * WV[d * TD + o];
    uL[o] = user_f32[(size_t)b * TD + o] + sv;
    __syncthreads();
    const int w = threadIdx.x >> 6, lane = threadIdx.x & 63;
    for (int k = w; k < NPRED; k += 6) {
        const int item = items[b * NPRED + k];
        const float* pwr = pw + (size_t)item * TD;
        float a = 0.f;
#pragma unroll
        for (int d = lane; d < TD; d += 64) a += pwr[d] * uL[d];
#pragma unroll
        for (int off = 32; off; off >>= 1) a += __shfl_down(a, off, 64);
        if (lane == 0) out_res[b * NPRED + k] = a + pb[item];
    }
}

extern "C" void kernel_launch(void* const* d_in, const int* in_sizes, int n_in,
                              void* d_out, int out_size, void* d_ws, size_t ws_size,
                              hipStream_t stream) {
    const float* node_emb  = (const float*)d_in[0];
    const float* predict_w = (const float*)d_in[1];
    const float* predict_b = (const float*)d_in[2];
    const float* basis     = (const float*)d_in[3];
    const float* comp      = (const float*)d_in[4];
    const float* root      = (const float*)d_in[5];
    const float* bias      = (const float*)d_in[6];
    const float* sbasis    = (const float*)d_in[7];
    const float* scomp     = (const float*)d_in[8];
    const float* sroot     = (const float*)d_in[9];
    const float* sbias     = (const float*)d_in[10];
    // d_in[11]=WQ, d_in[12]=WK: dead (softmax over summed axis collapses attention)
    const float* WV        = (const float*)d_in[13];
    const int* users       = (const int*)d_in[14];
    const int* seqs       = (const int*)d_in[15];
    const int* items       = (const int*)d_in[16];
    const int* eidx        = (const int*)d_in[17];
    const int* etyp        = (const int*)d_in[18];
    // d_in[19]=node_no: identity gather, dead
    const int* seidx       = (const int*)d_in[20];
    const int* setyp       = (const int*)d_in[21];

    // ---------------- workspace layout (~87 MB) ----------------
    float* xA     = (float*)d_ws;                       // [NNODE*64] f32
    float* xB     = xA + (size_t)NNODE * 64;            // [NNODE*64] f32
    u32*   Wp     = (u32*)(xB + (size_t)NNODE * 64);    // [NREL*64*32] f16 pairs
    u32*   Rp     = Wp + NREL * 64 * 32;                // [64*32] f16 pairs
    float* msum   = (float*)(Rp + 64 * 32);             // [BATCH*TD]
    int*   cnt    = (int*)(msum + (size_t)BATCH * TD);  // [NNODE] (reused per graph)
    int*   startB = cnt + NNODE;                        // [NNODE]
    int*   endB   = startB + NNODE;                     // [NNODE] (cursor -> row end)
    int*   startS = endB + NNODE;                       // [NNODE]
    int*   endS   = startS + NNODE;                     // [NNODE]
    int*   totals = endS + NNODE;                       // [2]
    u32*   packedB = (u32*)(totals + 2);                // [NEDGE]
    u32*   packedS = packedB + NEDGE;                   // [NSEDGE]

    float* out      = (float*)d_out;                  // reference outputs are float32
    float* out_res  = out;                            // [BATCH*NPRED]
    float* out_user = out + BATCH * NPRED;            // [BATCH*TD]
    float* out_seq  = out_user + (size_t)BATCH * TD;  // [BATCH*SEQL*TD]

    // ---------------- CSR build: big graph (reused for layers 0-2) ----------------
    hipMemsetAsync(totals, 0, 2 * sizeof(int), stream);
    hipMemsetAsync(cnt, 0, (size_t)NNODE * sizeof(int), stream);
    hist_kernel<<<2048, 256, 0, stream>>>(eidx + NEDGE, cnt, NEDGE);
    alloc_kernel<<<(NNODE + 255) / 256, 256, 0, stream>>>(cnt, startB, endB, totals + 0, NNODE);
    scatter_kernel<<<2048, 256, 0, stream>>>(eidx, eidx + NEDGE, etyp, endB, packedB, NEDGE);
    // ---------------- CSR build: short graph (layers 3-5) ----------------
    hipMemsetAsync(cnt, 0, (size_t)NNODE * sizeof(int), stream);
    hist_kernel<<<784, 256, 0, stream>>>(seidx + NSEDGE, cnt, NSEDGE);
    alloc_kernel<<<(NNODE + 255) / 256, 256, 0, stream>>>(cnt, startS, endS, totals + 1, NNODE);
    scatter_kernel<<<784, 256, 0, stream>>>(seidx, seidx + NSEDGE, setyp, endS, packedS, NSEDGE);

    const float* xc = node_emb;   // layer input (layer 0 reads node_emb directly)
    for (int l = 0; l < 6; ++l) {
        const float *bs, *cp, *rt, *bi;
        const int *rs, *re;
        const u32* pk;
        if (l < 3) {
            bs = basis  + (size_t)l * NB * DIM * DIM;
            cp = comp   + l * NREL * NB;
            rt = root   + l * DIM * DIM;
            bi = bias   + l * DIM;
            rs = startB; re = endB; pk = packedB;
        } else {
            const int m = l - 3;
            bs = sbasis + (size_t)m * NB * DIM * DIM;
            cp = scomp  + m * NREL * NB;
            rt = sroot  + m * DIM * DIM;
            bi = sbias  + m * DIM;
            rs = startS; re = endS; pk = packedS;
        }
        float* xg = (l & 1) ? xB : xA;                    // layer output buffer
        wpack_kernel<<<64, 256, 0, stream>>>(cp, bs, Wp);
        rpack_kernel<<<8, 256, 0, stream>>>(rt, Rp);
        rgcn_fused_kernel<<<512, 512, 0, stream>>>(xc, Wp, Rp, bi, rs, re, pk, xg, NNODE);
        gather_seq_kernel<<<320, 256, 0, stream>>>(xg, seqs, out_seq, l);
        user_msum_kernel<<<256, 256, 0, stream>>>(xg, users, seqs, msum, out_user, l);
        xc = xg;
    }

    final_kernel<<<BATCH, 384, 0, stream>>>(msum, out_user, WV, predict_w, predict_b,
                                            items, out_res);
}

// Round 2
// 1921.212 us; speedup vs baseline: 1.0965x; 1.0355x over previous
//
#include <hip/hip_runtime.h>
#include <hip/hip_fp16.h>

typedef unsigned short u16;
typedef unsigned int   u32;

#define DIM    64
#define NREL   8
#define NB     4
#define NNODE  150000
#define NEDGE  1000000
#define NSEDGE 200000
#define BATCH  1024
#define SEQL   20
#define NPRED  20
#define TD     384

// K layout for the fused GEMM: c = r*64 + d for r in [0,8) relations, c in [512,576) = self/root.
// Each c occupies TWO f16 slots k=2c (hi) and k=2c+1 (lo) -> K = 1152; both multiply Wstack[c].
#define KC     576
#define KH     1152
#define KTILES 36              // 1152 / 32
#define ROWD   580             // dwords per LDS X row (576 + 4 pad) = 2320 B
#define NODES_PER_TILE 32

typedef float    f32x4 __attribute__((ext_vector_type(4)));
typedef _Float16 f16x8 __attribute__((ext_vector_type(8)));

__device__ __forceinline__ u32 packsplit(float v) {
    __half h = __float2half_rn(v);
    __half l = __float2half_rn(v - __half2float(h));
    __half2 p; p.x = h; p.y = l;
    u32 r;
    __builtin_memcpy(&r, &p, 4);
    return r;
}

// ---- B-fragment pack: Wf[(kt*4+ct)*64 + lane] = 8 f16, lane l holds
//      B[k = kt*32 + (l>>4)*8 + u][j = ct*16 + (l&15)], B[k][j] = Wstack[k>>1][j]
//      Wstack[c][j] = (c<512) ? sum_b comp[c>>6][b]*basis[b][c&63][j] : root[c&63][j]
__global__ __launch_bounds__(256) void wpackf_kernel(const float* __restrict__ comp,
                                                     const float* __restrict__ basis,
                                                     const float* __restrict__ root,
                                                     u32* __restrict__ Wf) {
    int idx = blockIdx.x * 256 + threadIdx.x;        // KTILES*4*64 = 9216
    if (idx >= KTILES * 4 * 64) return;
    int l  = idx & 63;
    int f  = idx >> 6;
    int kt = f >> 2, ct = f & 3;
    int j  = ct * 16 + (l & 15);
    int kb = kt * 32 + (l >> 4) * 8;
    union { f16x8 v; u16 h[8]; } out;
#pragma unroll
    for (int u = 0; u < 8; ++u) {
        int c = (kb + u) >> 1;
        float v;
        if (c < 512) {
            int r = c >> 6, d = c & 63;
            v = comp[r * NB + 0] * basis[0 * 4096 + d * 64 + j]
              + comp[r * NB + 1] * basis[1 * 4096 + d * 64 + j]
              + comp[r * NB + 2] * basis[2 * 4096 + d * 64 + j]
              + comp[r * NB + 3] * basis[3 * 4096 + d * 64 + j];
        } else {
            int d = c & 63;
            v = root[d * 64 + j];
        }
        out.h[u] = (u16)__half_as_ushort(__float2half_rn(v));
    }
    *((f16x8*)Wf + idx) = out.v;
}

// =================== CSR preprocessing, grouped by (dst, rel) ===========

__global__ __launch_bounds__(256) void hist_kernel(const int* __restrict__ dst,
                                                   const int* __restrict__ typ,
                                                   int* __restrict__ cnt8, int E) {
    int i = blockIdx.x * 256 + threadIdx.x;
    const int stride = gridDim.x * 256;
    for (; i < E; i += stride) atomicAdd(&cnt8[dst[i] * NREL + typ[i]], 1);
}

// wave-scan range allocation over NNODE*NREL counters (range order irrelevant)
__global__ __launch_bounds__(256) void alloc_kernel(const int* __restrict__ cnt,
                                                    int* __restrict__ rstart,
                                                    int* __restrict__ cursor,
                                                    int* __restrict__ total, int N) {
    const int i = blockIdx.x * 256 + threadIdx.x;
    const int lane = threadIdx.x & 63;
    int deg = (i < N) ? cnt[i] : 0;
    int v = deg;
#pragma unroll
    for (int o = 1; o < 64; o <<= 1) {
        int u = __shfl_up(v, o, 64);
        if (lane >= o) v += u;
    }
    int base = 0;
    if (lane == 63) base = atomicAdd(total, v);
    base = __shfl(base, 63, 64);
    if (i < N) {
        const int st = base + v - deg;
        rstart[i] = st;
        cursor[i] = st;
    }
}

__global__ __launch_bounds__(256) void scatter_kernel(const int* __restrict__ src,
                                                      const int* __restrict__ dst,
                                                      const int* __restrict__ typ,
                                                      int* __restrict__ cursor8,
                                                      u32* __restrict__ psrc, int E) {
    int i = blockIdx.x * 256 + threadIdx.x;
    const int stride = gridDim.x * 256;
    for (; i < E; i += stride) {
        const int slot = atomicAdd(&cursor8[dst[i] * NREL + typ[i]], 1);
        psrc[slot] = (u32)src[i];
    }
}

// =================== fused RGCN layer via relation-factored MFMA GEMM ==========
// Per 32-node tile: phase1 (8 waves x 4 nodes): per-relation f32 vector sums of
// x[src] rows, written to LDS as interleaved f16 hi/lo pairs (K=1152); self row
// in slots c=512..575. phase2: [32 x 1152] @ [1152 x 64] via mfma 16x16x32 f16,
// epilogue bias+tanh+store. No atomics, no memset.
__global__ __launch_bounds__(512) void rgcn_mfma_kernel(const float* __restrict__ x,
                                                        const u32* __restrict__ Wf,
                                                        const float* __restrict__ bias,
                                                        const int* __restrict__ starts8,
                                                        const int* __restrict__ ends8,
                                                        const u32* __restrict__ psrc,
                                                        float* __restrict__ xout, int N) {
    __shared__ u32 Xl[NODES_PER_TILE * ROWD];        // 74,240 B
    const int lane = threadIdx.x & 63;
    const int w = threadIdx.x >> 6;                  // wave 0..7
    const int NT = (N + NODES_PER_TILE - 1) / NODES_PER_TILE;
    const int rr = lane >> 3, oo = lane & 7;         // prefetch: lane -> (rel, slot)
    const int l15 = lane & 15, g = lane >> 4;

    for (int tile = blockIdx.x; tile < NT; tile += gridDim.x) {
        const int base = tile * NODES_PER_TILE;
        // ---------------- phase 1: relation sums ----------------
        for (int u = 0; u < 4; ++u) {
            const int row = w * 4 + u;
            const int n = base + row;
            if (n < N) {
                const float xn = x[(size_t)n * 64 + lane];
                const int stl = starts8[n * NREL + rr];
                const int enl = ends8[n * NREL + rr];
                u32 pre = 0;
                if (stl + oo < enl) pre = psrc[stl + oo];
                u32* Xrow = Xl + row * ROWD;
                for (int r = 0; r < NREL; ++r) {
                    const int st = __shfl(stl, r * 8, 64);
                    const int en = __shfl(enl, r * 8, 64);
                    const int dd = en - st;
                    float acc = 0.f;
                    if (dd > 0) {
                        const int cl = (dd > 8 ? 8 : dd) - 1;
#pragma unroll
                        for (int t = 0; t < 8; ++t) {
                            const int tt = t > cl ? cl : t;
                            const int s = __shfl((int)pre, r * 8 + tt, 64);
                            const float v = x[(size_t)s * 64 + lane];
                            acc += (t <= cl) ? v : 0.f;
                        }
                        if (dd > 8) {                // rare: deg(n,r) > 8
                            for (int i = st + 8; i < en; i += 64) {
                                int mm = en - i; if (mm > 64) mm = 64;
                                int pk = (lane < mm) ? (int)psrc[i + lane] : 0;
                                for (int t = 0; t < mm; ++t) {
                                    const int s = __shfl(pk, t, 64);
                                    acc += x[(size_t)s * 64 + lane];
                                }
                            }
                        }
                    }
                    Xrow[r * 64 + lane] = packsplit(acc);   // c = r*64+lane
                }
                Xrow[512 + lane] = packsplit(xn);           // self/root slot
            }
        }
        __syncthreads();
        // ---------------- phase 2: MFMA GEMM + epilogue ----------------
        {
            const int rt = w >> 2, ct = w & 3;       // 2 row-tiles x 4 col-tiles
            const u32* Arow = Xl + (rt * 16 + l15) * ROWD + g * 4;
            const f16x8* Bf = (const f16x8*)Wf + ct * 64 + lane;
            f32x4 acc = {0.f, 0.f, 0.f, 0.f};
#pragma unroll 4
            for (int kt = 0; kt < KTILES; ++kt) {
                f16x8 a = *(const f16x8*)(Arow + kt * 16);  // kt*32 halfs
                f16x8 b = Bf[kt * 256];                     // frag (kt*4+ct)
                acc = __builtin_amdgcn_mfma_f32_16x16x32_f16(a, b, acc, 0, 0, 0);
            }
            const int col = ct * 16 + l15;
            const float bc = bias[col];
#pragma unroll
            for (int q = 0; q < 4; ++q) {
                const int n = base + rt * 16 + g * 4 + q;   // C row = (lane>>4)*4+reg
                if (n < N) xout[(size_t)n * 64 + col] = tanhf(acc[q] + bc);
            }
        }
        __syncthreads();
    }
}

// ---- gather sequence rows -> f32 output column block l ----
__global__ __launch_bounds__(256) void gather_seq_kernel(const float* __restrict__ xc,
                                                         const int* __restrict__ seqs,
                                                         float* __restrict__ out_seq, int l) {
    const int lane = threadIdx.x & 63;
    int wave = blockIdx.x * 4 + (threadIdx.x >> 6);
    const int nw = gridDim.x * 4;
    for (int p = wave; p < BATCH * SEQL; p += nw) {
        const int idx = seqs[p];
        out_seq[(size_t)p * TD + l * 64 + lane] = xc[(size_t)idx * 64 + lane];
    }
}

// ---- per-batch: user row (f32 out) and msum = sum_t seq rows ----
__global__ __launch_bounds__(256) void user_msum_kernel(const float* __restrict__ xc,
                                                        const int* __restrict__ users,
                                                        const int* __restrict__ seqs,
                                                        float* __restrict__ msum,
                                                        float* __restrict__ out_user, int l) {
    const int lane = threadIdx.x & 63;
    int wave = blockIdx.x * 4 + (threadIdx.x >> 6);
    const int nw = gridDim.x * 4;
    for (int b = wave; b < BATCH; b += nw) {
        out_user[(size_t)b * TD + l * 64 + lane] = xc[(size_t)users[b] * 64 + lane];
        float m = 0.f;
        for (int t = 0; t < SEQL; ++t)
            m += xc[(size_t)seqs[b * SEQL + t] * 64 + lane];
        msum[(size_t)b * TD + l * 64 + lane] = m;
    }
}

// ---- final: s = msum @ WV (attention collapsed); res = pw.(user+s) + pb ----
__global__ __launch_bounds__(384) void final_kernel(const float* __restrict__ msum,
                                                    const float* __restrict__ user_f32,
                                                    const float* __restrict__ WV,
                                                    const float* __restrict__ pw,
                                                    const float* __restrict__ pb,
                                                    const int* __restrict__ items,
                                                    float* __restrict__ out_res) {
    __shared__ float ms[TD];
    __shared__ float uL[TD];
    const int b = blockIdx.x;
    const int o = threadIdx.x;
    ms[o] = msum[(size_t)b * TD + o];
    __syncthreads();
    float sv = 0.f;
#pragma unroll 4
    for (int d = 0; d < TD; ++d) sv += ms[d] * WV[d * TD + o];
    uL[o] = user_f32[(size_t)b * TD + o] + sv;
    __syncthreads();
    const int w = threadIdx.x >> 6, lane = threadIdx.x & 63;
    for (int k = w; k < NPRED; k += 6) {
        const int item = items[b * NPRED + k];
        const float* pwr = pw + (size_t)item * TD;
        float a = 0.f;
#pragma unroll
        for (int d = lane; d < TD; d += 64) a += pwr[d] * uL[d];
#pragma unroll
        for (int off = 32; off; off >>= 1) a += __shfl_down(a, off, 64);
        if (lane == 0) out_res[b * NPRED + k] = a + pb[item];
    }
}

extern "C" void kernel_launch(void* const* d_in, const int* in_sizes, int n_in,
                              void* d_out, int out_size, void* d_ws, size_t ws_size,
                              hipStream_t stream) {
    const float* node_emb  = (const float*)d_in[0];
    const float* predict_w = (const float*)d_in[1];
    const float* predict_b = (const float*)d_in[2];
    const float* basis     = (const float*)d_in[3];
    const float* comp      = (const float*)d_in[4];
    const float* root      = (const float*)d_in[5];
    const float* bias      = (const float*)d_in[6];
    const float* sbasis    = (const float*)d_in[7];
    const float* scomp     = (const float*)d_in[8];
    const float* sroot     = (const float*)d_in[9];
    const float* sbias     = (const float*)d_in[10];
    // d_in[11]=WQ, d_in[12]=WK: dead (softmax over summed axis collapses attention)
    const float* WV        = (const float*)d_in[13];
    const int* users       = (const int*)d_in[14];
    const int* seqs        = (const int*)d_in[15];
    const int* items       = (const int*)d_in[16];
    const int* eidx        = (const int*)d_in[17];
    const int* etyp        = (const int*)d_in[18];
    // d_in[19]=node_no: identity gather, dead
    const int* seidx       = (const int*)d_in[20];
    const int* setyp       = (const int*)d_in[21];

    // ---------------- workspace layout (~107 MB) ----------------
    float* xA    = (float*)d_ws;                        // [NNODE*64]
    float* xB    = xA + (size_t)NNODE * 64;             // [NNODE*64]
    u32*   Wf    = (u32*)(xB + (size_t)NNODE * 64);     // [KTILES*4*64*4] = 18432 u32
    float* msum  = (float*)(Wf + KTILES * 4 * 64 * 4);  // [BATCH*TD]
    int*   cnt8  = (int*)(msum + (size_t)BATCH * TD);   // [NNODE*8]
    int*   stB   = cnt8 + (size_t)NNODE * NREL;         // [NNODE*8]
    int*   enB   = stB  + (size_t)NNODE * NREL;         // [NNODE*8]
    int*   stS   = enB  + (size_t)NNODE * NREL;         // [NNODE*8]
    int*   enS   = stS  + (size_t)NNODE * NREL;         // [NNODE*8]
    int*   totals= enS  + (size_t)NNODE * NREL;         // [4]
    u32*   pB    = (u32*)(totals + 4);                  // [NEDGE]
    u32*   pS    = pB + NEDGE;                          // [NSEDGE]

    float* out      = (float*)d_out;
    float* out_res  = out;                            // [BATCH*NPRED]
    float* out_user = out + BATCH * NPRED;            // [BATCH*TD]
    float* out_seq  = out_user + (size_t)BATCH * TD;  // [BATCH*SEQL*TD]

    const int N8 = NNODE * NREL;
    // ---------------- CSR build: big graph (layers 0-2) ----------------
    hipMemsetAsync(totals, 0, 4 * sizeof(int), stream);
    hipMemsetAsync(cnt8, 0, (size_t)N8 * sizeof(int), stream);
    hist_kernel<<<2048, 256, 0, stream>>>(eidx + NEDGE, etyp, cnt8, NEDGE);
    alloc_kernel<<<(N8 + 255) / 256, 256, 0, stream>>>(cnt8, stB, enB, totals + 0, N8);
    scatter_kernel<<<2048, 256, 0, stream>>>(eidx, eidx + NEDGE, etyp, enB, pB, NEDGE);
    // ---------------- CSR build: short graph (layers 3-5) ----------------
    hipMemsetAsync(cnt8, 0, (size_t)N8 * sizeof(int), stream);
    hist_kernel<<<784, 256, 0, stream>>>(seidx + NSEDGE, setyp, cnt8, NSEDGE);
    alloc_kernel<<<(N8 + 255) / 256, 256, 0, stream>>>(cnt8, stS, enS, totals + 1, N8);
    scatter_kernel<<<784, 256, 0, stream>>>(seidx, seidx + NSEDGE, setyp, enS, pS, NSEDGE);

    const float* xc = node_emb;
    for (int l = 0; l < 6; ++l) {
        const float *bs, *cp, *rt, *bi;
        const int *rs, *re;
        const u32* pk;
        if (l < 3) {
            bs = basis  + (size_t)l * NB * DIM * DIM;
            cp = comp   + l * NREL * NB;
            rt = root   + l * DIM * DIM;
            bi = bias   + l * DIM;
            rs = stB; re = enB; pk = pB;
        } else {
            const int m = l - 3;
            bs = sbasis + (size_t)m * NB * DIM * DIM;
            cp = scomp  + m * NREL * NB;
            rt = sroot  + m * DIM * DIM;
            bi = sbias  + m * DIM;
            rs = stS; re = enS; pk = pS;
        }
        float* xg = (l & 1) ? xB : xA;
        wpackf_kernel<<<36, 256, 0, stream>>>(cp, bs, rt, Wf);
        rgcn_mfma_kernel<<<512, 512, 0, stream>>>(xc, Wf, bi, rs, re, pk, xg, NNODE);
        gather_seq_kernel<<<320, 256, 0, stream>>>(xg, seqs, out_seq, l);
        user_msum_kernel<<<256, 256, 0, stream>>>(xg, users, seqs, msum, out_user, l);
        xc = xg;
    }

    final_kernel<<<BATCH, 384, 0, stream>>>(msum, out_user, WV, predict_w, predict_b,
                                            items, out_res);
}

// Round 3
// 1570.333 us; speedup vs baseline: 1.3415x; 1.2234x over previous
//
#include <hip/hip_runtime.h>
#include <hip/hip_fp16.h>

typedef unsigned short u16;
typedef unsigned int   u32;

#define DIM    64
#define NREL   8
#define NB     4
#define NNODE  150000
#define NEDGE  1000000
#define NSEDGE 200000
#define BATCH  1024
#define SEQL   20
#define NPRED  20
#define TD     384

// K layout for the fused GEMM: c = r*64 + d for r in [0,8) relations, c in [512,576) = self/root.
// Each c occupies TWO f16 slots k=2c (hi) and k=2c+1 (lo) -> K = 1152; both multiply Wstack[c].
#define KC     576
#define KH     1152
#define KTILES 36              // 1152 / 32
#define ROWD   580             // dwords per LDS X row (576 + 4 pad) = 2320 B
#define NODES_PER_TILE 16      // LDS 16*580*4 = 37,120 B -> 4 blocks/CU -> 32 waves/CU

typedef float    f32x4 __attribute__((ext_vector_type(4)));
typedef _Float16 f16x8 __attribute__((ext_vector_type(8)));

__device__ __forceinline__ u32 packsplit(float v) {
    __half h = __float2half_rn(v);
    __half l = __float2half_rn(v - __half2float(h));
    __half2 p; p.x = h; p.y = l;
    u32 r;
    __builtin_memcpy(&r, &p, 4);
    return r;
}

// ---- B-fragment pack: Wf[(kt*4+ct)*64 + lane] = 8 f16, lane l holds
//      B[k = kt*32 + (l>>4)*8 + u][j = ct*16 + (l&15)], B[k][j] = Wstack[k>>1][j]
//      Wstack[c][j] = (c<512) ? sum_b comp[c>>6][b]*basis[b][c&63][j] : root[c&63][j]
__global__ __launch_bounds__(256) void wpackf_kernel(const float* __restrict__ comp,
                                                     const float* __restrict__ basis,
                                                     const float* __restrict__ root,
                                                     u32* __restrict__ Wf) {
    int idx = blockIdx.x * 256 + threadIdx.x;        // KTILES*4*64 = 9216
    if (idx >= KTILES * 4 * 64) return;
    int l  = idx & 63;
    int f  = idx >> 6;
    int kt = f >> 2, ct = f & 3;
    int j  = ct * 16 + (l & 15);
    int kb = kt * 32 + (l >> 4) * 8;
    union { f16x8 v; u16 h[8]; } out;
#pragma unroll
    for (int u = 0; u < 8; ++u) {
        int c = (kb + u) >> 1;
        float v;
        if (c < 512) {
            int r = c >> 6, d = c & 63;
            v = comp[r * NB + 0] * basis[0 * 4096 + d * 64 + j]
              + comp[r * NB + 1] * basis[1 * 4096 + d * 64 + j]
              + comp[r * NB + 2] * basis[2 * 4096 + d * 64 + j]
              + comp[r * NB + 3] * basis[3 * 4096 + d * 64 + j];
        } else {
            int d = c & 63;
            v = root[d * 64 + j];
        }
        out.h[u] = (u16)__half_as_ushort(__float2half_rn(v));
    }
    *((f16x8*)Wf + idx) = out.v;
}

// =================== CSR preprocessing, grouped by (dst, rel) ===========
// NOTE: alloc_kernel's wave-scan allocates entries i = n*8+r consecutively within a
// 64-entry wave (8 whole nodes), so a node's 8 relation ranges are CONTIGUOUS and in
// relation order: [starts8[n*8], ends8[n*8+7]) is the node's full edge list.

__global__ __launch_bounds__(256) void hist_kernel(const int* __restrict__ dst,
                                                   const int* __restrict__ typ,
                                                   int* __restrict__ cnt8, int E) {
    int i = blockIdx.x * 256 + threadIdx.x;
    const int stride = gridDim.x * 256;
    for (; i < E; i += stride) atomicAdd(&cnt8[dst[i] * NREL + typ[i]], 1);
}

__global__ __launch_bounds__(256) void alloc_kernel(const int* __restrict__ cnt,
                                                    int* __restrict__ rstart,
                                                    int* __restrict__ cursor,
                                                    int* __restrict__ total, int N) {
    const int i = blockIdx.x * 256 + threadIdx.x;
    const int lane = threadIdx.x & 63;
    int deg = (i < N) ? cnt[i] : 0;
    int v = deg;
#pragma unroll
    for (int o = 1; o < 64; o <<= 1) {
        int u = __shfl_up(v, o, 64);
        if (lane >= o) v += u;
    }
    int base = 0;
    if (lane == 63) base = atomicAdd(total, v);
    base = __shfl(base, 63, 64);
    if (i < N) {
        const int st = base + v - deg;
        rstart[i] = st;
        cursor[i] = st;
    }
}

__global__ __launch_bounds__(256) void scatter_kernel(const int* __restrict__ src,
                                                      const int* __restrict__ dst,
                                                      const int* __restrict__ typ,
                                                      int* __restrict__ cursor8,
                                                      u32* __restrict__ psrc, int E) {
    int i = blockIdx.x * 256 + threadIdx.x;
    const int stride = gridDim.x * 256;
    for (; i < E; i += stride) {
        const int slot = atomicAdd(&cursor8[dst[i] * NREL + typ[i]], 1);
        psrc[slot] = (u32)src[i];
    }
}

// =================== fused RGCN layer via relation-factored MFMA GEMM ==========
// Per 16-node tile: phase1 (8 waves x 2 nodes): per-relation f32 vector sums of
// x[src] rows (degree-exact loops over the node's contiguous prefetched edge list),
// written to LDS as interleaved f16 hi/lo pairs (K=1152); self row in c=512..575.
// phase2 (waves 0-3): [16 x 1152] @ [1152 x 64] via mfma 16x16x32 f16,
// epilogue bias+tanh+store. No atomics, no memset.
__global__ __launch_bounds__(512) void rgcn_mfma_kernel(const float* __restrict__ x,
                                                        const u32* __restrict__ Wf,
                                                        const float* __restrict__ bias,
                                                        const int* __restrict__ starts8,
                                                        const int* __restrict__ ends8,
                                                        const u32* __restrict__ psrc,
                                                        float* __restrict__ xout, int N) {
    __shared__ u32 Xl[NODES_PER_TILE * ROWD];        // 37,120 B
    const int lane = threadIdx.x & 63;
    const int w = threadIdx.x >> 6;                  // wave 0..7
    const int NT = (N + NODES_PER_TILE - 1) / NODES_PER_TILE;
    const int l15 = lane & 15, g = lane >> 4;

    for (int tile = blockIdx.x; tile < NT; tile += gridDim.x) {
        const int base = tile * NODES_PER_TILE;
        // ---------------- phase 1: relation sums (degree-exact) ----------------
        for (int u = 0; u < 2; ++u) {
            const int row = w * 2 + u;
            const int n = base + row;
            if (n < N) {
                u32* Xrow = Xl + row * ROWD;
                const float xn = x[(size_t)n * 64 + lane];
                const int stl = starts8[n * NREL + (lane & 7)];
                const int enl = ends8[n * NREL + (lane & 7)];
                const int st0 = __shfl(stl, 0, 64);
                const int en7 = __shfl(enl, 7, 64);
                if (en7 - st0 <= 64) {               // common: whole node in one window
                    const u32 pk = (lane < en7 - st0) ? psrc[st0 + lane] : 0u;
#pragma unroll
                    for (int r = 0; r < NREL; ++r) {
                        const int st = __shfl(stl, r, 64) - st0;
                        const int en = __shfl(enl, r, 64) - st0;
                        float a0 = 0.f, a1 = 0.f;
                        int i = st;
                        for (; i + 1 < en; i += 2) {
                            const int s0 = (int)__shfl((int)pk, i, 64);
                            const int s1 = (int)__shfl((int)pk, i + 1, 64);
                            a0 += x[(size_t)s0 * 64 + lane];
                            a1 += x[(size_t)s1 * 64 + lane];
                        }
                        if (i < en) {
                            const int s0 = (int)__shfl((int)pk, i, 64);
                            a0 += x[(size_t)s0 * 64 + lane];
                        }
                        Xrow[r * 64 + lane] = packsplit(a0 + a1);
                    }
                } else {                             // rare: degree > 64, chunked
#pragma unroll 1
                    for (int r = 0; r < NREL; ++r) {
                        const int st = __shfl(stl, r, 64);
                        const int en = __shfl(enl, r, 64);
                        float acc = 0.f;
                        for (int i2 = st; i2 < en; i2 += 64) {
                            int mm = en - i2; if (mm > 64) mm = 64;
                            int pkc = (lane < mm) ? (int)psrc[i2 + lane] : 0;
                            for (int t = 0; t < mm; ++t) {
                                const int s = __shfl(pkc, t, 64);
                                acc += x[(size_t)s * 64 + lane];
                            }
                        }
                        Xrow[r * 64 + lane] = packsplit(acc);
                    }
                }
                Xrow[512 + lane] = packsplit(xn);    // self/root slot
            }
        }
        __syncthreads();
        // ---------------- phase 2: MFMA GEMM + epilogue (waves 0-3) ----------------
        if (w < 4) {
            const int ct = w;                        // 4 col-tiles of 16
            const u32* Arow = Xl + l15 * ROWD + g * 4;
            const f16x8* Bf = (const f16x8*)Wf + ct * 64 + lane;
            f32x4 acc = {0.f, 0.f, 0.f, 0.f};
#pragma unroll 4
            for (int kt = 0; kt < KTILES; ++kt) {
                f16x8 a = *(const f16x8*)(Arow + kt * 16);  // kt*32 halfs
                f16x8 b = Bf[kt * 256];                     // frag (kt*4+ct)
                acc = __builtin_amdgcn_mfma_f32_16x16x32_f16(a, b, acc, 0, 0, 0);
            }
            const int col = ct * 16 + l15;
            const float bc = bias[col];
#pragma unroll
            for (int q = 0; q < 4; ++q) {
                const int n = base + g * 4 + q;      // C row = (lane>>4)*4+reg
                if (n < N) xout[(size_t)n * 64 + col] = tanhf(acc[q] + bc);
            }
        }
        __syncthreads();
    }
}

// ---- per-layer postprocessing: seq gather + user row + msum, one kernel ----
__global__ __launch_bounds__(256) void post_kernel(const float* __restrict__ xc,
                                                   const int* __restrict__ users,
                                                   const int* __restrict__ seqs,
                                                   float* __restrict__ msum,
                                                   float* __restrict__ out_user,
                                                   float* __restrict__ out_seq, int l) {
    const int lane = threadIdx.x & 63;
    int wave = blockIdx.x * 4 + (threadIdx.x >> 6);
    const int nw = gridDim.x * 4;
    for (int p = wave; p < BATCH * SEQL; p += nw) {
        const int idx = seqs[p];
        out_seq[(size_t)p * TD + l * 64 + lane] = xc[(size_t)idx * 64 + lane];
    }
    for (int b = wave; b < BATCH; b += nw) {
        out_user[(size_t)b * TD + l * 64 + lane] = xc[(size_t)users[b] * 64 + lane];
        float m = 0.f;
        for (int t = 0; t < SEQL; ++t)
            m += xc[(size_t)seqs[b * SEQL + t] * 64 + lane];
        msum[(size_t)b * TD + l * 64 + lane] = m;
    }
}

// ---- final: s = msum @ WV (attention collapsed); res = pw.(user+s) + pb ----
__global__ __launch_bounds__(384) void final_kernel(const float* __restrict__ msum,
                                                    const float* __restrict__ user_f32,
                                                    const float* __restrict__ WV,
                                                    const float* __restrict__ pw,
                                                    const float* __restrict__ pb,
                                                    const int* __restrict__ items,
                                                    float* __restrict__ out_res) {
    __shared__ float ms[TD];
    __shared__ float uL[TD];
    const int b = blockIdx.x;
    const int o = threadIdx.x;
    ms[o] = msum[(size_t)b * TD + o];
    __syncthreads();
    float sv = 0.f;
#pragma unroll 4
    for (int d = 0; d < TD; ++d) sv += ms[d] * WV[d * TD + o];
    uL[o] = user_f32[(size_t)b * TD + o] + sv;
    __syncthreads();
    const int w = threadIdx.x >> 6, lane = threadIdx.x & 63;
    for (int k = w; k < NPRED; k += 6) {
        const int item = items[b * NPRED + k];
        const float* pwr = pw + (size_t)item * TD;
        float a = 0.f;
#pragma unroll
        for (int d = lane; d < TD; d += 64) a += pwr[d] * uL[d];
#pragma unroll
        for (int off = 32; off; off >>= 1) a += __shfl_down(a, off, 64);
        if (lane == 0) out_res[b * NPRED + k] = a + pb[item];
    }
}

extern "C" void kernel_launch(void* const* d_in, const int* in_sizes, int n_in,
                              void* d_out, int out_size, void* d_ws, size_t ws_size,
                              hipStream_t stream) {
    const float* node_emb  = (const float*)d_in[0];
    const float* predict_w = (const float*)d_in[1];
    const float* predict_b = (const float*)d_in[2];
    const float* basis     = (const float*)d_in[3];
    const float* comp      = (const float*)d_in[4];
    const float* root      = (const float*)d_in[5];
    const float* bias      = (const float*)d_in[6];
    const float* sbasis    = (const float*)d_in[7];
    const float* scomp     = (const float*)d_in[8];
    const float* sroot     = (const float*)d_in[9];
    const float* sbias     = (const float*)d_in[10];
    // d_in[11]=WQ, d_in[12]=WK: dead (softmax over summed axis collapses attention)
    const float* WV        = (const float*)d_in[13];
    const int* users       = (const int*)d_in[14];
    const int* seqs        = (const int*)d_in[15];
    const int* items       = (const int*)d_in[16];
    const int* eidx        = (const int*)d_in[17];
    const int* etyp        = (const int*)d_in[18];
    // d_in[19]=node_no: identity gather, dead
    const int* seidx       = (const int*)d_in[20];
    const int* setyp       = (const int*)d_in[21];

    // ---------------- workspace layout (~107 MB) ----------------
    float* xA    = (float*)d_ws;                        // [NNODE*64]
    float* xB    = xA + (size_t)NNODE * 64;             // [NNODE*64]
    u32*   Wf    = (u32*)(xB + (size_t)NNODE * 64);     // [KTILES*4*64*4] = 18432 u32
    float* msum  = (float*)(Wf + KTILES * 4 * 64 * 4);  // [BATCH*TD]
    int*   cnt8  = (int*)(msum + (size_t)BATCH * TD);   // [NNODE*8]
    int*   stB   = cnt8 + (size_t)NNODE * NREL;         // [NNODE*8]
    int*   enB   = stB  + (size_t)NNODE * NREL;         // [NNODE*8]
    int*   stS   = enB  + (size_t)NNODE * NREL;         // [NNODE*8]
    int*   enS   = stS  + (size_t)NNODE * NREL;         // [NNODE*8]
    int*   totals= enS  + (size_t)NNODE * NREL;         // [4]
    u32*   pB    = (u32*)(totals + 4);                  // [NEDGE]
    u32*   pS    = pB + NEDGE;                          // [NSEDGE]

    float* out      = (float*)d_out;
    float* out_res  = out;                            // [BATCH*NPRED]
    float* out_user = out + BATCH * NPRED;            // [BATCH*TD]
    float* out_seq  = out_user + (size_t)BATCH * TD;  // [BATCH*SEQL*TD]

    const int N8 = NNODE * NREL;
    // ---------------- CSR build: big graph (layers 0-2) ----------------
    hipMemsetAsync(totals, 0, 4 * sizeof(int), stream);
    hipMemsetAsync(cnt8, 0, (size_t)N8 * sizeof(int), stream);
    hist_kernel<<<2048, 256, 0, stream>>>(eidx + NEDGE, etyp, cnt8, NEDGE);
    alloc_kernel<<<(N8 + 255) / 256, 256, 0, stream>>>(cnt8, stB, enB, totals + 0, N8);
    scatter_kernel<<<2048, 256, 0, stream>>>(eidx, eidx + NEDGE, etyp, enB, pB, NEDGE);
    // ---------------- CSR build: short graph (layers 3-5) ----------------
    hipMemsetAsync(cnt8, 0, (size_t)N8 * sizeof(int), stream);
    hist_kernel<<<784, 256, 0, stream>>>(seidx + NSEDGE, setyp, cnt8, NSEDGE);
    alloc_kernel<<<(N8 + 255) / 256, 256, 0, stream>>>(cnt8, stS, enS, totals + 1, N8);
    scatter_kernel<<<784, 256, 0, stream>>>(seidx, seidx + NSEDGE, setyp, enS, pS, NSEDGE);

    const float* xc = node_emb;
    for (int l = 0; l < 6; ++l) {
        const float *bs, *cp, *rt, *bi;
        const int *rs, *re;
        const u32* pk;
        if (l < 3) {
            bs = basis  + (size_t)l * NB * DIM * DIM;
            cp = comp   + l * NREL * NB;
            rt = root   + l * DIM * DIM;
            bi = bias   + l * DIM;
            rs = stB; re = enB; pk = pB;
        } else {
            const int m = l - 3;
            bs = sbasis + (size_t)m * NB * DIM * DIM;
            cp = scomp  + m * NREL * NB;
            rt = sroot  + m * DIM * DIM;
            bi = sbias  + m * DIM;
            rs = stS; re = enS; pk = pS;
        }
        float* xg = (l & 1) ? xB : xA;
        wpackf_kernel<<<36, 256, 0, stream>>>(cp, bs, rt, Wf);
        rgcn_mfma_kernel<<<2048, 512, 0, stream>>>(xc, Wf, bi, rs, re, pk, xg, NNODE);
        post_kernel<<<320, 256, 0, stream>>>(xg, users, seqs, msum, out_user, out_seq, l);
        xc = xg;
    }

    final_kernel<<<BATCH, 384, 0, stream>>>(msum, out_user, WV, predict_w, predict_b,
                                            items, out_res);
}

// Round 4
// 1168.535 us; speedup vs baseline: 1.8028x; 1.3438x over previous
//
#include <hip/hip_runtime.h>
#include <hip/hip_fp16.h>

typedef unsigned short u16;
typedef unsigned int   u32;

#define DIM    64
#define NREL   8
#define NB     4
#define NNODE  150000
#define NEDGE  1000000
#define NSEDGE 200000
#define BATCH  1024
#define SEQL   20
#define NPRED  20
#define TD     384

// K layout for the fused GEMM: c = r*64 + d for r in [0,8) relations, c in [512,576) = self/root.
// Each c occupies TWO f16 slots k=2c (hi) and k=2c+1 (lo) -> K = 1152; both multiply Wstack[c].
#define KC     576
#define KH     1152
#define KTILES 36              // 1152 / 32
#define ROWD   580             // dwords per LDS X row (576 + 4 pad) = 2320 B
#define NODES_PER_TILE 16      // LDS 16*580*4 = 37,120 B -> 4 blocks/CU -> 32 waves/CU

#define SCAN_CHUNK 2048        // elements per 256-thread block in the CSR scan

typedef float    f32x4 __attribute__((ext_vector_type(4)));
typedef _Float16 f16x8 __attribute__((ext_vector_type(8)));

__device__ __forceinline__ u32 packsplit(float v) {
    __half h = __float2half_rn(v);
    __half l = __float2half_rn(v - __half2float(h));
    __half2 p; p.x = h; p.y = l;
    u32 r;
    __builtin_memcpy(&r, &p, 4);
    return r;
}

// ---- B-fragment pack: Wf[(kt*4+ct)*64 + lane] = 8 f16, lane l holds
//      B[k = kt*32 + (l>>4)*8 + u][j = ct*16 + (l&15)], B[k][j] = Wstack[k>>1][j]
//      Wstack[c][j] = (c<512) ? sum_b comp[c>>6][b]*basis[b][c&63][j] : root[c&63][j]
__global__ __launch_bounds__(256) void wpackf_kernel(const float* __restrict__ comp,
                                                     const float* __restrict__ basis,
                                                     const float* __restrict__ root,
                                                     u32* __restrict__ Wf) {
    int idx = blockIdx.x * 256 + threadIdx.x;        // KTILES*4*64 = 9216
    if (idx >= KTILES * 4 * 64) return;
    int l  = idx & 63;
    int f  = idx >> 6;
    int kt = f >> 2, ct = f & 3;
    int j  = ct * 16 + (l & 15);
    int kb = kt * 32 + (l >> 4) * 8;
    union { f16x8 v; u16 h[8]; } out;
#pragma unroll
    for (int u = 0; u < 8; ++u) {
        int c = (kb + u) >> 1;
        float v;
        if (c < 512) {
            int r = c >> 6, d = c & 63;
            v = comp[r * NB + 0] * basis[0 * 4096 + d * 64 + j]
              + comp[r * NB + 1] * basis[1 * 4096 + d * 64 + j]
              + comp[r * NB + 2] * basis[2 * 4096 + d * 64 + j]
              + comp[r * NB + 3] * basis[3 * 4096 + d * 64 + j];
        } else {
            int d = c & 63;
            v = root[d * 64 + j];
        }
        out.h[u] = (u16)__half_as_ushort(__float2half_rn(v));
    }
    *((f16x8*)Wf + idx) = out.v;
}

// =================== CSR preprocessing, grouped by (dst, rel) ===========
// True index-ordered exclusive scan over cnt8 -> node n's 8 relation ranges are
// exactly consecutive in relation order: [starts8[n*8], ends8[n*8+7]) is the node's
// full edge list. No serialized global atomics (the R3 alloc_kernel burned 217 us
// on a single global cursor line).

__global__ __launch_bounds__(256) void hist_kernel(const int* __restrict__ dst,
                                                   const int* __restrict__ typ,
                                                   int* __restrict__ cnt8, int E) {
    int i = blockIdx.x * 256 + threadIdx.x;
    const int stride = gridDim.x * 256;
    for (; i < E; i += stride) atomicAdd(&cnt8[dst[i] * NREL + typ[i]], 1);
}

// pass 1: per-block sums (block = SCAN_CHUNK elements, 8 per thread)
__global__ __launch_bounds__(256) void blocksum_kernel(const int* __restrict__ cnt,
                                                       int* __restrict__ bsum, int N) {
    const int base = blockIdx.x * SCAN_CHUNK + threadIdx.x * 8;
    int s = 0;
#pragma unroll
    for (int u = 0; u < 8; ++u) {
        const int i = base + u;
        s += (i < N) ? cnt[i] : 0;
    }
#pragma unroll
    for (int o = 1; o < 64; o <<= 1) s += __shfl_xor(s, o, 64);
    __shared__ int ws[4];
    if ((threadIdx.x & 63) == 0) ws[threadIdx.x >> 6] = s;
    __syncthreads();
    if (threadIdx.x == 0) bsum[blockIdx.x] = ws[0] + ws[1] + ws[2] + ws[3];
}

// pass 2: single-block exclusive scan of block sums (B <= 1024)
__global__ __launch_bounds__(1024) void scanbsum_kernel(int* __restrict__ bsum, int B) {
    __shared__ int sh[1024];
    const int t = threadIdx.x;
    const int v = (t < B) ? bsum[t] : 0;
    sh[t] = v;
    __syncthreads();
    for (int o = 1; o < 1024; o <<= 1) {
        const int u = (t >= o) ? sh[t - o] : 0;
        __syncthreads();
        sh[t] += u;
        __syncthreads();
    }
    if (t < B) bsum[t] = sh[t] - v;                  // exclusive
}

// pass 3: per-element exclusive scan, write rstart + cursor
__global__ __launch_bounds__(256) void alloc2_kernel(const int* __restrict__ cnt,
                                                     const int* __restrict__ bsum,
                                                     int* __restrict__ rstart,
                                                     int* __restrict__ cursor, int N) {
    const int base = blockIdx.x * SCAN_CHUNK + threadIdx.x * 8;
    const int lane = threadIdx.x & 63;
    int c[8];
    int s = 0;
#pragma unroll
    for (int u = 0; u < 8; ++u) {
        const int i = base + u;
        c[u] = (i < N) ? cnt[i] : 0;
        s += c[u];
    }
    int v = s;
#pragma unroll
    for (int o = 1; o < 64; o <<= 1) {
        const int u2 = __shfl_up(v, o, 64);
        if (lane >= o) v += u2;
    }
    __shared__ int ws[4];
    if (lane == 63) ws[threadIdx.x >> 6] = v;
    __syncthreads();
    const int wv = threadIdx.x >> 6;
    int waveoff = 0;
#pragma unroll
    for (int k = 0; k < 4; ++k) waveoff += (k < wv) ? ws[k] : 0;
    int tbase = bsum[blockIdx.x] + waveoff + (v - s);
#pragma unroll
    for (int u = 0; u < 8; ++u) {
        const int i = base + u;
        if (i < N) {
            rstart[i] = tbase;
            cursor[i] = tbase;
            tbase += c[u];
        }
    }
}

__global__ __launch_bounds__(256) void scatter_kernel(const int* __restrict__ src,
                                                      const int* __restrict__ dst,
                                                      const int* __restrict__ typ,
                                                      int* __restrict__ cursor8,
                                                      u32* __restrict__ psrc, int E) {
    int i = blockIdx.x * 256 + threadIdx.x;
    const int stride = gridDim.x * 256;
    for (; i < E; i += stride) {
        const int slot = atomicAdd(&cursor8[dst[i] * NREL + typ[i]], 1);
        psrc[slot] = (u32)src[i];
    }
}

// =================== fused RGCN layer via relation-factored MFMA GEMM ==========
// Per 16-node tile: phase1 (8 waves x 2 nodes): per-relation f32 vector sums of
// x[src] rows (degree-exact loops over the node's contiguous prefetched edge list),
// written to LDS as interleaved f16 hi/lo pairs (K=1152); self row in c=512..575.
// phase2 (waves 0-3): [16 x 1152] @ [1152 x 64] via mfma 16x16x32 f16,
// epilogue bias+tanh+store. No atomics, no memset.
__global__ __launch_bounds__(512) void rgcn_mfma_kernel(const float* __restrict__ x,
                                                        const u32* __restrict__ Wf,
                                                        const float* __restrict__ bias,
                                                        const int* __restrict__ starts8,
                                                        const int* __restrict__ ends8,
                                                        const u32* __restrict__ psrc,
                                                        float* __restrict__ xout, int N) {
    __shared__ u32 Xl[NODES_PER_TILE * ROWD];        // 37,120 B
    const int lane = threadIdx.x & 63;
    const int w = threadIdx.x >> 6;                  // wave 0..7
    const int NT = (N + NODES_PER_TILE - 1) / NODES_PER_TILE;
    const int l15 = lane & 15, g = lane >> 4;

    for (int tile = blockIdx.x; tile < NT; tile += gridDim.x) {
        const int base = tile * NODES_PER_TILE;
        // ---------------- phase 1: relation sums (degree-exact) ----------------
        for (int u = 0; u < 2; ++u) {
            const int row = w * 2 + u;
            const int n = base + row;
            if (n < N) {
                u32* Xrow = Xl + row * ROWD;
                const float xn = x[(size_t)n * 64 + lane];
                const int stl = starts8[n * NREL + (lane & 7)];
                const int enl = ends8[n * NREL + (lane & 7)];
                const int st0 = __shfl(stl, 0, 64);
                const int en7 = __shfl(enl, 7, 64);
                if (en7 - st0 <= 64) {               // common: whole node in one window
                    const u32 pk = (lane < en7 - st0) ? psrc[st0 + lane] : 0u;
#pragma unroll
                    for (int r = 0; r < NREL; ++r) {
                        const int st = __shfl(stl, r, 64) - st0;
                        const int en = __shfl(enl, r, 64) - st0;
                        float a0 = 0.f, a1 = 0.f;
                        int i = st;
                        for (; i + 1 < en; i += 2) {
                            const int s0 = (int)__shfl((int)pk, i, 64);
                            const int s1 = (int)__shfl((int)pk, i + 1, 64);
                            a0 += x[(size_t)s0 * 64 + lane];
                            a1 += x[(size_t)s1 * 64 + lane];
                        }
                        if (i < en) {
                            const int s0 = (int)__shfl((int)pk, i, 64);
                            a0 += x[(size_t)s0 * 64 + lane];
                        }
                        Xrow[r * 64 + lane] = packsplit(a0 + a1);
                    }
                } else {                             // rare: degree > 64, chunked
#pragma unroll 1
                    for (int r = 0; r < NREL; ++r) {
                        const int st = __shfl(stl, r, 64);
                        const int en = __shfl(enl, r, 64);
                        float acc = 0.f;
                        for (int i2 = st; i2 < en; i2 += 64) {
                            int mm = en - i2; if (mm > 64) mm = 64;
                            int pkc = (lane < mm) ? (int)psrc[i2 + lane] : 0;
                            for (int t = 0; t < mm; ++t) {
                                const int s = __shfl(pkc, t, 64);
                                acc += x[(size_t)s * 64 + lane];
                            }
                        }
                        Xrow[r * 64 + lane] = packsplit(acc);
                    }
                }
                Xrow[512 + lane] = packsplit(xn);    // self/root slot
            }
        }
        __syncthreads();
        // ---------------- phase 2: MFMA GEMM + epilogue (waves 0-3) ----------------
        if (w < 4) {
            const int ct = w;                        // 4 col-tiles of 16
            const u32* Arow = Xl + l15 * ROWD + g * 4;
            const f16x8* Bf = (const f16x8*)Wf + ct * 64 + lane;
            f32x4 acc = {0.f, 0.f, 0.f, 0.f};
#pragma unroll 4
            for (int kt = 0; kt < KTILES; ++kt) {
                f16x8 a = *(const f16x8*)(Arow + kt * 16);  // kt*32 halfs
                f16x8 b = Bf[kt * 256];                     // frag (kt*4+ct)
                acc = __builtin_amdgcn_mfma_f32_16x16x32_f16(a, b, acc, 0, 0, 0);
            }
            const int col = ct * 16 + l15;
            const float bc = bias[col];
#pragma unroll
            for (int q = 0; q < 4; ++q) {
                const int n = base + g * 4 + q;      // C row = (lane>>4)*4+reg
                if (n < N) xout[(size_t)n * 64 + col] = tanhf(acc[q] + bc);
            }
        }
        __syncthreads();
    }
}

// ---- per-layer postprocessing: seq gather + user row + msum, one kernel ----
__global__ __launch_bounds__(256) void post_kernel(const float* __restrict__ xc,
                                                   const int* __restrict__ users,
                                                   const int* __restrict__ seqs,
                                                   float* __restrict__ msum,
                                                   float* __restrict__ out_user,
                                                   float* __restrict__ out_seq, int l) {
    const int lane = threadIdx.x & 63;
    int wave = blockIdx.x * 4 + (threadIdx.x >> 6);
    const int nw = gridDim.x * 4;
    for (int p = wave; p < BATCH * SEQL; p += nw) {
        const int idx = seqs[p];
        out_seq[(size_t)p * TD + l * 64 + lane] = xc[(size_t)idx * 64 + lane];
    }
    for (int b = wave; b < BATCH; b += nw) {
        out_user[(size_t)b * TD + l * 64 + lane] = xc[(size_t)users[b] * 64 + lane];
        float m = 0.f;
        for (int t = 0; t < SEQL; ++t)
            m += xc[(size_t)seqs[b * SEQL + t] * 64 + lane];
        msum[(size_t)b * TD + l * 64 + lane] = m;
    }
}

// ---- final: s = msum @ WV (attention collapsed); res = pw.(user+s) + pb ----
__global__ __launch_bounds__(384) void final_kernel(const float* __restrict__ msum,
                                                    const float* __restrict__ user_f32,
                                                    const float* __restrict__ WV,
                                                    const float* __restrict__ pw,
                                                    const float* __restrict__ pb,
                                                    const int* __restrict__ items,
                                                    float* __restrict__ out_res) {
    __shared__ float ms[TD];
    __shared__ float uL[TD];
    const int b = blockIdx.x;
    const int o = threadIdx.x;
    ms[o] = msum[(size_t)b * TD + o];
    __syncthreads();
    float sv = 0.f;
#pragma unroll 4
    for (int d = 0; d < TD; ++d) sv += ms[d] * WV[d * TD + o];
    uL[o] = user_f32[(size_t)b * TD + o] + sv;
    __syncthreads();
    const int w = threadIdx.x >> 6, lane = threadIdx.x & 63;
    for (int k = w; k < NPRED; k += 6) {
        const int item = items[b * NPRED + k];
        const float* pwr = pw + (size_t)item * TD;
        float a = 0.f;
#pragma unroll
        for (int d = lane; d < TD; d += 64) a += pwr[d] * uL[d];
#pragma unroll
        for (int off = 32; off; off >>= 1) a += __shfl_down(a, off, 64);
        if (lane == 0) out_res[b * NPRED + k] = a + pb[item];
    }
}

extern "C" void kernel_launch(void* const* d_in, const int* in_sizes, int n_in,
                              void* d_out, int out_size, void* d_ws, size_t ws_size,
                              hipStream_t stream) {
    const float* node_emb  = (const float*)d_in[0];
    const float* predict_w = (const float*)d_in[1];
    const float* predict_b = (const float*)d_in[2];
    const float* basis     = (const float*)d_in[3];
    const float* comp      = (const float*)d_in[4];
    const float* root      = (const float*)d_in[5];
    const float* bias      = (const float*)d_in[6];
    const float* sbasis    = (const float*)d_in[7];
    const float* scomp     = (const float*)d_in[8];
    const float* sroot     = (const float*)d_in[9];
    const float* sbias     = (const float*)d_in[10];
    // d_in[11]=WQ, d_in[12]=WK: dead (softmax over summed axis collapses attention)
    const float* WV        = (const float*)d_in[13];
    const int* users       = (const int*)d_in[14];
    const int* seqs        = (const int*)d_in[15];
    const int* items       = (const int*)d_in[16];
    const int* eidx        = (const int*)d_in[17];
    const int* etyp        = (const int*)d_in[18];
    // d_in[19]=node_no: identity gather, dead
    const int* seidx       = (const int*)d_in[20];
    const int* setyp       = (const int*)d_in[21];

    // ---------------- workspace layout (~107 MB) ----------------
    float* xA    = (float*)d_ws;                        // [NNODE*64]
    float* xB    = xA + (size_t)NNODE * 64;             // [NNODE*64]
    u32*   Wf    = (u32*)(xB + (size_t)NNODE * 64);     // [KTILES*4*64*4] = 18432 u32
    float* msum  = (float*)(Wf + KTILES * 4 * 64 * 4);  // [BATCH*TD]
    int*   cnt8  = (int*)(msum + (size_t)BATCH * TD);   // [NNODE*8]
    int*   stB   = cnt8 + (size_t)NNODE * NREL;         // [NNODE*8]
    int*   enB   = stB  + (size_t)NNODE * NREL;         // [NNODE*8]
    int*   stS   = enB  + (size_t)NNODE * NREL;         // [NNODE*8]
    int*   enS   = stS  + (size_t)NNODE * NREL;         // [NNODE*8]
    int*   bsum  = enS  + (size_t)NNODE * NREL;         // [1024]
    u32*   pB    = (u32*)(bsum + 1024);                 // [NEDGE]
    u32*   pS    = pB + NEDGE;                          // [NSEDGE]

    float* out      = (float*)d_out;
    float* out_res  = out;                            // [BATCH*NPRED]
    float* out_user = out + BATCH * NPRED;            // [BATCH*TD]
    float* out_seq  = out_user + (size_t)BATCH * TD;  // [BATCH*SEQL*TD]

    const int N8 = NNODE * NREL;
    const int NBLK = (N8 + SCAN_CHUNK - 1) / SCAN_CHUNK;   // 586
    // ---------------- CSR build: big graph (layers 0-2) ----------------
    hipMemsetAsync(cnt8, 0, (size_t)N8 * sizeof(int), stream);
    hist_kernel<<<2048, 256, 0, stream>>>(eidx + NEDGE, etyp, cnt8, NEDGE);
    blocksum_kernel<<<NBLK, 256, 0, stream>>>(cnt8, bsum, N8);
    scanbsum_kernel<<<1, 1024, 0, stream>>>(bsum, NBLK);
    alloc2_kernel<<<NBLK, 256, 0, stream>>>(cnt8, bsum, stB, enB, N8);
    scatter_kernel<<<2048, 256, 0, stream>>>(eidx, eidx + NEDGE, etyp, enB, pB, NEDGE);
    // ---------------- CSR build: short graph (layers 3-5) ----------------
    hipMemsetAsync(cnt8, 0, (size_t)N8 * sizeof(int), stream);
    hist_kernel<<<784, 256, 0, stream>>>(seidx + NSEDGE, setyp, cnt8, NSEDGE);
    blocksum_kernel<<<NBLK, 256, 0, stream>>>(cnt8, bsum, N8);
    scanbsum_kernel<<<1, 1024, 0, stream>>>(bsum, NBLK);
    alloc2_kernel<<<NBLK, 256, 0, stream>>>(cnt8, bsum, stS, enS, N8);
    scatter_kernel<<<784, 256, 0, stream>>>(seidx, seidx + NSEDGE, setyp, enS, pS, NSEDGE);

    const float* xc = node_emb;
    for (int l = 0; l < 6; ++l) {
        const float *bs, *cp, *rt, *bi;
        const int *rs, *re;
        const u32* pk;
        if (l < 3) {
            bs = basis  + (size_t)l * NB * DIM * DIM;
            cp = comp   + l * NREL * NB;
            rt = root   + l * DIM * DIM;
            bi = bias   + l * DIM;
            rs = stB; re = enB; pk = pB;
        } else {
            const int m = l - 3;
            bs = sbasis + (size_t)m * NB * DIM * DIM;
            cp = scomp  + m * NREL * NB;
            rt = sroot  + m * DIM * DIM;
            bi = sbias  + m * DIM;
            rs = stS; re = enS; pk = pS;
        }
        float* xg = (l & 1) ? xB : xA;
        wpackf_kernel<<<36, 256, 0, stream>>>(cp, bs, rt, Wf);
        rgcn_mfma_kernel<<<2048, 512, 0, stream>>>(xc, Wf, bi, rs, re, pk, xg, NNODE);
        post_kernel<<<320, 256, 0, stream>>>(xg, users, seqs, msum, out_user, out_seq, l);
        xc = xg;
    }

    final_kernel<<<BATCH, 384, 0, stream>>>(msum, out_user, WV, predict_w, predict_b,
                                            items, out_res);
}

// Round 5
// 1044.620 us; speedup vs baseline: 2.0167x; 1.1186x over previous
//
#include <hip/hip_runtime.h>
#include <hip/hip_fp16.h>

typedef unsigned short u16;
typedef unsigned int   u32;

#define DIM    64
#define NREL   8
#define NB     4
#define NNODE  150000
#define NEDGE  1000000
#define NSEDGE 200000
#define BATCH  1024
#define SEQL   20
#define NPRED  20
#define TD     384

// K layout for the fused GEMM: c = r*64 + d for r in [0,8) relations, c in [512,576) = self/root.
// Each c occupies TWO f16 slots k=2c (hi) and k=2c+1 (lo) -> K = 1152; both multiply Wstack[c].
#define KC     576
#define KH     1152
#define KTILES 36              // 1152 / 32
#define ROWD   580             // dwords per LDS X row (576 + 4 pad) = 2320 B
#define NODES_PER_TILE 16      // LDS 16*580*4 = 37,120 B -> 4 blocks/CU -> 32 waves/CU

#define SCAN_CHUNK 2048        // elements per 256-thread block in the CSR scan

typedef float    f32x4 __attribute__((ext_vector_type(4)));
typedef _Float16 f16x8 __attribute__((ext_vector_type(8)));

__device__ __forceinline__ u32 packsplit(float v) {
    __half h = __float2half_rn(v);
    __half l = __float2half_rn(v - __half2float(h));
    __half2 p; p.x = h; p.y = l;
    u32 r;
    __builtin_memcpy(&r, &p, 4);
    return r;
}

// ---- B-fragment pack: Wf[(kt*4+ct)*64 + lane] = 8 f16, lane l holds
//      B[k = kt*32 + (l>>4)*8 + u][j = ct*16 + (l&15)], B[k][j] = Wstack[k>>1][j]
//      Wstack[c][j] = (c<512) ? sum_b comp[c>>6][b]*basis[b][c&63][j] : root[c&63][j]
__global__ __launch_bounds__(256) void wpackf_kernel(const float* __restrict__ comp,
                                                     const float* __restrict__ basis,
                                                     const float* __restrict__ root,
                                                     u32* __restrict__ Wf) {
    int idx = blockIdx.x * 256 + threadIdx.x;        // KTILES*4*64 = 9216
    if (idx >= KTILES * 4 * 64) return;
    int l  = idx & 63;
    int f  = idx >> 6;
    int kt = f >> 2, ct = f & 3;
    int j  = ct * 16 + (l & 15);
    int kb = kt * 32 + (l >> 4) * 8;
    union { f16x8 v; u16 h[8]; } out;
#pragma unroll
    for (int u = 0; u < 8; ++u) {
        int c = (kb + u) >> 1;
        float v;
        if (c < 512) {
            int r = c >> 6, d = c & 63;
            v = comp[r * NB + 0] * basis[0 * 4096 + d * 64 + j]
              + comp[r * NB + 1] * basis[1 * 4096 + d * 64 + j]
              + comp[r * NB + 2] * basis[2 * 4096 + d * 64 + j]
              + comp[r * NB + 3] * basis[3 * 4096 + d * 64 + j];
        } else {
            int d = c & 63;
            v = root[d * 64 + j];
        }
        out.h[u] = (u16)__half_as_ushort(__float2half_rn(v));
    }
    *((f16x8*)Wf + idx) = out.v;
}

// =================== CSR preprocessing, grouped by (dst, rel) ===========
// True index-ordered exclusive scan over cnt8 -> node n's full edge list is the
// contiguous window [starts8[n*8], ends8[n*8+7]). psrc packs src | rel<<18.

__global__ __launch_bounds__(256) void hist_kernel(const int* __restrict__ dst,
                                                   const int* __restrict__ typ,
                                                   int* __restrict__ cnt8, int E) {
    int i = blockIdx.x * 256 + threadIdx.x;
    const int stride = gridDim.x * 256;
    for (; i < E; i += stride) atomicAdd(&cnt8[dst[i] * NREL + typ[i]], 1);
}

// pass 1: per-block sums (block = SCAN_CHUNK elements, 8 per thread)
__global__ __launch_bounds__(256) void blocksum_kernel(const int* __restrict__ cnt,
                                                       int* __restrict__ bsum, int N) {
    const int base = blockIdx.x * SCAN_CHUNK + threadIdx.x * 8;
    int s = 0;
#pragma unroll
    for (int u = 0; u < 8; ++u) {
        const int i = base + u;
        s += (i < N) ? cnt[i] : 0;
    }
#pragma unroll
    for (int o = 1; o < 64; o <<= 1) s += __shfl_xor(s, o, 64);
    __shared__ int ws[4];
    if ((threadIdx.x & 63) == 0) ws[threadIdx.x >> 6] = s;
    __syncthreads();
    if (threadIdx.x == 0) bsum[blockIdx.x] = ws[0] + ws[1] + ws[2] + ws[3];
}

// pass 2: single-block exclusive scan of block sums (B <= 1024)
__global__ __launch_bounds__(1024) void scanbsum_kernel(int* __restrict__ bsum, int B) {
    __shared__ int sh[1024];
    const int t = threadIdx.x;
    const int v = (t < B) ? bsum[t] : 0;
    sh[t] = v;
    __syncthreads();
    for (int o = 1; o < 1024; o <<= 1) {
        const int u = (t >= o) ? sh[t - o] : 0;
        __syncthreads();
        sh[t] += u;
        __syncthreads();
    }
    if (t < B) bsum[t] = sh[t] - v;                  // exclusive
}

// pass 3: per-element exclusive scan, write rstart + cursor
__global__ __launch_bounds__(256) void alloc2_kernel(const int* __restrict__ cnt,
                                                     const int* __restrict__ bsum,
                                                     int* __restrict__ rstart,
                                                     int* __restrict__ cursor, int N) {
    const int base = blockIdx.x * SCAN_CHUNK + threadIdx.x * 8;
    const int lane = threadIdx.x & 63;
    int c[8];
    int s = 0;
#pragma unroll
    for (int u = 0; u < 8; ++u) {
        const int i = base + u;
        c[u] = (i < N) ? cnt[i] : 0;
        s += c[u];
    }
    int v = s;
#pragma unroll
    for (int o = 1; o < 64; o <<= 1) {
        const int u2 = __shfl_up(v, o, 64);
        if (lane >= o) v += u2;
    }
    __shared__ int ws[4];
    if (lane == 63) ws[threadIdx.x >> 6] = v;
    __syncthreads();
    const int wv = threadIdx.x >> 6;
    int waveoff = 0;
#pragma unroll
    for (int k = 0; k < 4; ++k) waveoff += (k < wv) ? ws[k] : 0;
    int tbase = bsum[blockIdx.x] + waveoff + (v - s);
#pragma unroll
    for (int u = 0; u < 8; ++u) {
        const int i = base + u;
        if (i < N) {
            rstart[i] = tbase;
            cursor[i] = tbase;
            tbase += c[u];
        }
    }
}

__global__ __launch_bounds__(256) void scatter_kernel(const int* __restrict__ src,
                                                      const int* __restrict__ dst,
                                                      const int* __restrict__ typ,
                                                      int* __restrict__ cursor8,
                                                      u32* __restrict__ psrc, int E) {
    int i = blockIdx.x * 256 + threadIdx.x;
    const int stride = gridDim.x * 256;
    for (; i < E; i += stride) {
        const int slot = atomicAdd(&cursor8[dst[i] * NREL + typ[i]], 1);
        psrc[slot] = (u32)src[i] | ((u32)typ[i] << 18);   // src < 2^18, rel < 8
    }
}

// =================== fused RGCN layer via relation-factored MFMA GEMM ==========
// Per 16-node tile: phase1 (8 waves x 2 nodes): ONE flat degree-proportional edge
// loop per node (rel from psrc bits), f32 accumulation directly in the LDS A-row,
// 4-way unrolled (4 x-row gathers in flight); both nodes' headers + pk windows
// prefetched upfront. Convert pass packs f16 hi/lo pairs (K=1152); self row in
// c=512..575. phase2 (waves 0-3): [16 x 1152] @ [1152 x 64] via mfma 16x16x32 f16,
// epilogue bias+tanh+store. No atomics, no memset.
__global__ __launch_bounds__(512) void rgcn_mfma_kernel(const float* __restrict__ x,
                                                        const u32* __restrict__ Wf,
                                                        const float* __restrict__ bias,
                                                        const int* __restrict__ starts8,
                                                        const int* __restrict__ ends8,
                                                        const u32* __restrict__ psrc,
                                                        float* __restrict__ xout, int N) {
    __shared__ u32 Xl[NODES_PER_TILE * ROWD];        // 37,120 B
    const int lane = threadIdx.x & 63;
    const int w = threadIdx.x >> 6;                  // wave 0..7
    const int NT = (N + NODES_PER_TILE - 1) / NODES_PER_TILE;
    const int l15 = lane & 15, g = lane >> 4;

    for (int tile = blockIdx.x; tile < NT; tile += gridDim.x) {
        const int base = tile * NODES_PER_TILE;
        const int n0 = base + w * 2;
        // ---- prefetch both nodes' headers + self rows (independent loads) ----
        int nst0 = 0, nen0 = 0, nst1 = 0, nen1 = 0;
        float xn0 = 0.f, xn1 = 0.f;
        if (n0 < N) {
            nst0 = starts8[n0 * NREL];
            nen0 = ends8[n0 * NREL + 7];
            xn0  = x[(size_t)n0 * 64 + lane];
        }
        if (n0 + 1 < N) {
            nst1 = starts8[(n0 + 1) * NREL];
            nen1 = ends8[(n0 + 1) * NREL + 7];
            xn1  = x[(size_t)(n0 + 1) * 64 + lane];
        }
        // ---- prefetch both pk windows ----
        u32 pk0 = 0, pk1 = 0;
        if (lane < nen0 - nst0) pk0 = psrc[nst0 + lane];
        if (lane < nen1 - nst1) pk1 = psrc[nst1 + lane];
#pragma unroll
        for (int u = 0; u < 2; ++u) {
            const int n = n0 + u;
            if (n < N) {
                const int row = w * 2 + u;
                u32* Xrow = Xl + row * ROWD;
                float* XrowF = (float*)Xrow;
#pragma unroll
                for (int r = 0; r < NREL; ++r) XrowF[r * 64 + lane] = 0.f;
                const u32 pk = u ? pk1 : pk0;
                const int nst = u ? nst1 : nst0;
                const int nen = u ? nen1 : nen0;
                const int tot = nen - nst;
                const int cw = tot > 64 ? 64 : tot;
                int t = 0;
                for (; t + 4 <= cw; t += 4) {
                    const u32 p0 = __shfl(pk, t + 0, 64);
                    const u32 p1 = __shfl(pk, t + 1, 64);
                    const u32 p2 = __shfl(pk, t + 2, 64);
                    const u32 p3 = __shfl(pk, t + 3, 64);
                    const float v0 = x[(size_t)(p0 & 0x3FFFFu) * 64 + lane];
                    const float v1 = x[(size_t)(p1 & 0x3FFFFu) * 64 + lane];
                    const float v2 = x[(size_t)(p2 & 0x3FFFFu) * 64 + lane];
                    const float v3 = x[(size_t)(p3 & 0x3FFFFu) * 64 + lane];
                    XrowF[(p0 >> 18) * 64 + lane] += v0;
                    XrowF[(p1 >> 18) * 64 + lane] += v1;
                    XrowF[(p2 >> 18) * 64 + lane] += v2;
                    XrowF[(p3 >> 18) * 64 + lane] += v3;
                }
                for (; t < cw; ++t) {
                    const u32 p = __shfl(pk, t, 64);
                    XrowF[(p >> 18) * 64 + lane] += x[(size_t)(p & 0x3FFFFu) * 64 + lane];
                }
                if (tot > 64) {                      // rare: degree > 64, chunked
                    for (int i2 = nst + 64; i2 < nen; i2 += 64) {
                        int mm = nen - i2; if (mm > 64) mm = 64;
                        const u32 pkc = (lane < mm) ? psrc[i2 + lane] : 0u;
                        for (int tt = 0; tt < mm; ++tt) {
                            const u32 p = __shfl(pkc, tt, 64);
                            XrowF[(p >> 18) * 64 + lane] += x[(size_t)(p & 0x3FFFFu) * 64 + lane];
                        }
                    }
                }
                // convert f32 accum -> packed f16 hi/lo pairs, in place
#pragma unroll
                for (int r = 0; r < NREL; ++r)
                    Xrow[r * 64 + lane] = packsplit(XrowF[r * 64 + lane]);
                Xrow[512 + lane] = packsplit(u ? xn1 : xn0);   // self/root slot
            }
        }
        __syncthreads();
        // ---------------- phase 2: MFMA GEMM + epilogue (waves 0-3) ----------------
        if (w < 4) {
            const int ct = w;                        // 4 col-tiles of 16
            const u32* Arow = Xl + l15 * ROWD + g * 4;
            const f16x8* Bf = (const f16x8*)Wf + ct * 64 + lane;
            f32x4 acc = {0.f, 0.f, 0.f, 0.f};
#pragma unroll 4
            for (int kt = 0; kt < KTILES; ++kt) {
                f16x8 a = *(const f16x8*)(Arow + kt * 16);  // kt*32 halfs
                f16x8 b = Bf[kt * 256];                     // frag (kt*4+ct)
                acc = __builtin_amdgcn_mfma_f32_16x16x32_f16(a, b, acc, 0, 0, 0);
            }
            const int col = ct * 16 + l15;
            const float bc = bias[col];
#pragma unroll
            for (int q = 0; q < 4; ++q) {
                const int n = base + g * 4 + q;      // C row = (lane>>4)*4+reg
                if (n < N) xout[(size_t)n * 64 + col] = tanhf(acc[q] + bc);
            }
        }
        __syncthreads();
    }
}

// ---- per-layer postprocessing: seq gather + user row + msum, one kernel ----
__global__ __launch_bounds__(256) void post_kernel(const float* __restrict__ xc,
                                                   const int* __restrict__ users,
                                                   const int* __restrict__ seqs,
                                                   float* __restrict__ msum,
                                                   float* __restrict__ out_user,
                                                   float* __restrict__ out_seq, int l) {
    const int lane = threadIdx.x & 63;
    int wave = blockIdx.x * 4 + (threadIdx.x >> 6);
    const int nw = gridDim.x * 4;
    for (int p = wave; p < BATCH * SEQL; p += nw) {
        const int idx = seqs[p];
        out_seq[(size_t)p * TD + l * 64 + lane] = xc[(size_t)idx * 64 + lane];
    }
    for (int b = wave; b < BATCH; b += nw) {
        out_user[(size_t)b * TD + l * 64 + lane] = xc[(size_t)users[b] * 64 + lane];
        float m = 0.f;
        for (int t = 0; t < SEQL; ++t)
            m += xc[(size_t)seqs[b * SEQL + t] * 64 + lane];
        msum[(size_t)b * TD + l * 64 + lane] = m;
    }
}

// ---- final: s = msum @ WV (attention collapsed); res = pw.(user+s) + pb ----
__global__ __launch_bounds__(384) void final_kernel(const float* __restrict__ msum,
                                                    const float* __restrict__ user_f32,
                                                    const float* __restrict__ WV,
                                                    const float* __restrict__ pw,
                                                    const float* __restrict__ pb,
                                                    const int* __restrict__ items,
                                                    float* __restrict__ out_res) {
    __shared__ float ms[TD];
    __shared__ float uL[TD];
    const int b = blockIdx.x;
    const int o = threadIdx.x;
    ms[o] = msum[(size_t)b * TD + o];
    __syncthreads();
    float sv = 0.f;
#pragma unroll 4
    for (int d = 0; d < TD; ++d) sv += ms[d] * WV[d * TD + o];
    uL[o] = user_f32[(size_t)b * TD + o] + sv;
    __syncthreads();
    const int w = threadIdx.x >> 6, lane = threadIdx.x & 63;
    for (int k = w; k < NPRED; k += 6) {
        const int item = items[b * NPRED + k];
        const float* pwr = pw + (size_t)item * TD;
        float a = 0.f;
#pragma unroll
        for (int d = lane; d < TD; d += 64) a += pwr[d] * uL[d];
#pragma unroll
        for (int off = 32; off; off >>= 1) a += __shfl_down(a, off, 64);
        if (lane == 0) out_res[b * NPRED + k] = a + pb[item];
    }
}

extern "C" void kernel_launch(void* const* d_in, const int* in_sizes, int n_in,
                              void* d_out, int out_size, void* d_ws, size_t ws_size,
                              hipStream_t stream) {
    const float* node_emb  = (const float*)d_in[0];
    const float* predict_w = (const float*)d_in[1];
    const float* predict_b = (const float*)d_in[2];
    const float* basis     = (const float*)d_in[3];
    const float* comp      = (const float*)d_in[4];
    const float* root      = (const float*)d_in[5];
    const float* bias      = (const float*)d_in[6];
    const float* sbasis    = (const float*)d_in[7];
    const float* scomp     = (const float*)d_in[8];
    const float* sroot     = (const float*)d_in[9];
    const float* sbias     = (const float*)d_in[10];
    // d_in[11]=WQ, d_in[12]=WK: dead (softmax over summed axis collapses attention)
    const float* WV        = (const float*)d_in[13];
    const int* users       = (const int*)d_in[14];
    const int* seqs        = (const int*)d_in[15];
    const int* items       = (const int*)d_in[16];
    const int* eidx        = (const int*)d_in[17];
    const int* etyp        = (const int*)d_in[18];
    // d_in[19]=node_no: identity gather, dead
    const int* seidx       = (const int*)d_in[20];
    const int* setyp       = (const int*)d_in[21];

    // ---------------- workspace layout (~107 MB) ----------------
    float* xA    = (float*)d_ws;                        // [NNODE*64]
    float* xB    = xA + (size_t)NNODE * 64;             // [NNODE*64]
    u32*   Wf    = (u32*)(xB + (size_t)NNODE * 64);     // [KTILES*4*64*4] = 18432 u32
    float* msum  = (float*)(Wf + KTILES * 4 * 64 * 4);  // [BATCH*TD]
    int*   cnt8  = (int*)(msum + (size_t)BATCH * TD);   // [NNODE*8]
    int*   stB   = cnt8 + (size_t)NNODE * NREL;         // [NNODE*8]
    int*   enB   = stB  + (size_t)NNODE * NREL;         // [NNODE*8]
    int*   stS   = enB  + (size_t)NNODE * NREL;         // [NNODE*8]
    int*   enS   = stS  + (size_t)NNODE * NREL;         // [NNODE*8]
    int*   bsum  = enS  + (size_t)NNODE * NREL;         // [1024]
    u32*   pB    = (u32*)(bsum + 1024);                 // [NEDGE]
    u32*   pS    = pB + NEDGE;                          // [NSEDGE]

    float* out      = (float*)d_out;
    float* out_res  = out;                            // [BATCH*NPRED]
    float* out_user = out + BATCH * NPRED;            // [BATCH*TD]
    float* out_seq  = out_user + (size_t)BATCH * TD;  // [BATCH*SEQL*TD]

    const int N8 = NNODE * NREL;
    const int NBLK = (N8 + SCAN_CHUNK - 1) / SCAN_CHUNK;   // 586
    // ---------------- CSR build: big graph (layers 0-2) ----------------
    hipMemsetAsync(cnt8, 0, (size_t)N8 * sizeof(int), stream);
    hist_kernel<<<2048, 256, 0, stream>>>(eidx + NEDGE, etyp, cnt8, NEDGE);
    blocksum_kernel<<<NBLK, 256, 0, stream>>>(cnt8, bsum, N8);
    scanbsum_kernel<<<1, 1024, 0, stream>>>(bsum, NBLK);
    alloc2_kernel<<<NBLK, 256, 0, stream>>>(cnt8, bsum, stB, enB, N8);
    scatter_kernel<<<2048, 256, 0, stream>>>(eidx, eidx + NEDGE, etyp, enB, pB, NEDGE);
    // ---------------- CSR build: short graph (layers 3-5) ----------------
    hipMemsetAsync(cnt8, 0, (size_t)N8 * sizeof(int), stream);
    hist_kernel<<<784, 256, 0, stream>>>(seidx + NSEDGE, setyp, cnt8, NSEDGE);
    blocksum_kernel<<<NBLK, 256, 0, stream>>>(cnt8, bsum, N8);
    scanbsum_kernel<<<1, 1024, 0, stream>>>(bsum, NBLK);
    alloc2_kernel<<<NBLK, 256, 0, stream>>>(cnt8, bsum, stS, enS, N8);
    scatter_kernel<<<784, 256, 0, stream>>>(seidx, seidx + NSEDGE, setyp, enS, pS, NSEDGE);

    const float* xc = node_emb;
    for (int l = 0; l < 6; ++l) {
        const float *bs, *cp, *rt, *bi;
        const int *rs, *re;
        const u32* pk;
        if (l < 3) {
            bs = basis  + (size_t)l * NB * DIM * DIM;
            cp = comp   + l * NREL * NB;
            rt = root   + l * DIM * DIM;
            bi = bias   + l * DIM;
            rs = stB; re = enB; pk = pB;
        } else {
            const int m = l - 3;
            bs = sbasis + (size_t)m * NB * DIM * DIM;
            cp = scomp  + m * NREL * NB;
            rt = sroot  + m * DIM * DIM;
            bi = sbias  + m * DIM;
            rs = stS; re = enS; pk = pS;
        }
        float* xg = (l & 1) ? xB : xA;
        wpackf_kernel<<<36, 256, 0, stream>>>(cp, bs, rt, Wf);
        rgcn_mfma_kernel<<<2048, 512, 0, stream>>>(xc, Wf, bi, rs, re, pk, xg, NNODE);
        post_kernel<<<320, 256, 0, stream>>>(xg, users, seqs, msum, out_user, out_seq, l);
        xc = xg;
    }

    final_kernel<<<BATCH, 384, 0, stream>>>(msum, out_user, WV, predict_w, predict_b,
                                            items, out_res);
}